// Round 9
// baseline (1327.764 us; speedup 1.0000x reference)
//
#include <hip/hip_runtime.h>
#include <math.h>

// Problem constants (fixed by the reference): B=256, S=2048, I=32, H=128, O=1
#define B_ 256
#define S_ 2048
#define I_ 32
#define H_ 128
#define BPB 2   // batches per block: 16 waves; waves [0,8) -> slot 0, [8,16) -> slot 1

typedef float v2f __attribute__((ext_vector_type(2)));
__device__ __forceinline__ v2f mk2(float a, float b) { v2f r; r.x = a; r.y = b; return r; }

// Packed fp32 FMA (VOP3P, gfx90a+ CDNA line): d.{x,y} += a.{x,y} * b.{x,y}.
// _lo/_hi variants splat one half of `a` to both lanes via op_sel -- used to
// broadcast a single value against a weight pair without splat movs.
__device__ __forceinline__ void pk_fma_lo(v2f& d, v2f a, v2f b) {
    asm("v_pk_fma_f32 %0, %1, %2, %0 op_sel:[0,0,0] op_sel_hi:[0,1,1]"
        : "+v"(d) : "v"(a), "v"(b));
}
__device__ __forceinline__ void pk_fma_hi(v2f& d, v2f a, v2f b) {
    asm("v_pk_fma_f32 %0, %1, %2, %0 op_sel:[1,0,0] op_sel_hi:[1,1,1]"
        : "+v"(d) : "v"(a), "v"(b));
}

// Barrier WITHOUT vmcnt(0) drain (HIP __syncthreads waits vmcnt(0) before
// s_barrier, stalling on in-flight global prefetch/stores every step).
// LDS visibility only needs lgkmcnt(0).
__device__ __forceinline__ void sync_lds() {
    asm volatile("" ::: "memory");
    asm volatile("s_waitcnt lgkmcnt(0)" ::: "memory");
    __builtin_amdgcn_s_barrier();
    asm volatile("" ::: "memory");
}

// tanh(z) = 1 - 2/(e^{2z}+1); exact limits at +-inf, abs err ~1e-7.
__device__ __forceinline__ float fast_tanh(float z) {
    float e = __expf(2.0f * z);
    return 1.0f - 2.0f / (e + 1.0f);
}

template <int CTRL>
__device__ __forceinline__ float dppf(float v) {
    return __int_as_float(__builtin_amdgcn_update_dpp(
        0, __float_as_int(v), CTRL, 0xF, 0xF, false));
}
// DPP controls: 0xB1 = quad_perm [1,0,3,2] (xor1), 0x4E = quad_perm [2,3,0,1]
// (xor2), 0x141 = row_half_mirror (l^7), 0x128 = row_ror:8 (l^8 in 16-row).

// xor16 via ds_swizzle BitMode (proven r3-r8, absmax ~0). Only in the lag-2
// combiner -- off the per-step critical path.
__device__ __forceinline__ float swz_xor16(float v) {
    return __int_as_float(__builtin_amdgcn_ds_swizzle(__float_as_int(v), 0x401F));
}

// h0 LDS layout: 16 chunks of 8 h values, chunk pitch 12 floats (48B).
// 48B stride => 16 distinct b128 addrs alias banks only 2-way (free, m136);
// the 4 lanes sharing a kg4 read the SAME addr (broadcast, no conflict).
#define CHP 12

// Packed Wh MACs for one float4 of h0 (4 consecutive k): 8 pk_fma covering
// 4 h outputs. acc01 = h-pair (hb,hb+1), acc23 = (hb+2,hb+3).
#define PKD(hv, base)                                             \
    pk_fma_lo(acc01, mk2((hv).x, (hv).y), W01[(base) + 0]);       \
    pk_fma_lo(acc23, mk2((hv).x, (hv).y), W23[(base) + 0]);       \
    pk_fma_hi(acc01, mk2((hv).x, (hv).y), W01[(base) + 1]);       \
    pk_fma_hi(acc23, mk2((hv).x, (hv).y), W23[(base) + 1]);       \
    pk_fma_lo(acc01, mk2((hv).z, (hv).w), W01[(base) + 2]);       \
    pk_fma_lo(acc23, mk2((hv).z, (hv).w), W23[(base) + 2]);       \
    pk_fma_hi(acc01, mk2((hv).z, (hv).w), W01[(base) + 3]);       \
    pk_fma_hi(acc23, mk2((hv).z, (hv).w), W23[(base) + 3]);

// Per-step score/proj partial reduce (deferred 1 step): 2 DPP stages
// (xor1 = b0, xor2 = b1 -- the role bits, summing the 4 roles' h).
// Remaining bits {b4,b5} go to pl_lds as 4 group-partials per class per
// wave; the lag-2 combiner absorbs them. Class bit = b2 (dup), spare dup =
// b3. Writers: b0=b1=b3=0 -> (l & 0xB) == 0, 8 lanes = 2 classes x 4 groups.
#define UP_REDUCE(RING)                                                       \
    {                                                                         \
      float r = uP;                                                           \
      r += dppf<0xB1>(r);                                                     \
      r += dppf<0x4E>(r);                                                     \
      if ((l & 0xB) == 0)                                                     \
        ((float*)&pl_lds[bb][RING][(w << 2) | ((l >> 4) & 3)])[(l >> 2) & 1] = r; \
    }

// Lag-2 combiner over 32 float2 entries (8 waves x 4 groups): 5-level tree
// (xor1, xor2, xor4 via half_mirror, xor8 via ror:8, xor16 via swizzle).
// Run by role-wave (s&7) of EACH batch slot: rotates per phase, no straggler.
#define PL_COMBINE(RING, SIDX)                                                \
    {                                                                         \
      float2 pp = pl_lds[bb][RING][l & 31];                                   \
      float px = pp.x, py = pp.y;                                             \
      px += dppf<0xB1>(px);  py += dppf<0xB1>(py);                            \
      px += dppf<0x4E>(px);  py += dppf<0x4E>(py);                            \
      px += dppf<0x141>(px); py += dppf<0x141>(py);                           \
      px += dppf<0x128>(px); py += dppf<0x128>(py);                           \
      px += swz_xor16(px);   py += swz_xor16(py);                             \
      if (l == 0) part[((SIDX) << 8) + b] = make_float2(px, py);              \
    }

// Matvec core, 4h x 8k per lane: TWO ds_read_b128. Lane bits: k-group =
// b0..b3 (kg4, 16 groups x 8 k), h-group = b4,b5; final-h role = b0 + 2*b1.
// x.Wi (i-chunk of 2 = {2kg4, 2kg4+1}) and the bias (gated kg4==0) are
// FOLDED INTO THE ACC INIT so they ride the same reduction tree.
// Tree: stage0 = PURE half_mirror (mask 7) on all 4 accs -- BEFORE any role
// select, so it never mixes h; then xor1 (+sel b0), xor2 (+sel b1), xor8
// (pure, b3). Span {7,1,2}+{8} covers all 16 k-groups; bias enters once.
// (r8 step, proven absmax 0.0.)
#define MAT_CORE(XS)                                                          \
    v2f acc01 = bias01, acc23 = bias23;                                       \
    pk_fma_lo(acc01, mk2((XS).x, (XS).y), WiF01[0]);                          \
    pk_fma_hi(acc01, mk2((XS).x, (XS).y), WiF01[1]);                          \
    pk_fma_lo(acc23, mk2((XS).x, (XS).y), WiF23[0]);                          \
    pk_fma_hi(acc23, mk2((XS).x, (XS).y), WiF23[1]);                          \
    PKD(hvA, 0) PKD(hvB, 4)                                                   \
    float p0 = acc01.x + dppf<0x141>(acc01.x);                                \
    float p1 = acc01.y + dppf<0x141>(acc01.y);                                \
    float p2 = acc23.x + dppf<0x141>(acc23.x);                                \
    float p3 = acc23.y + dppf<0x141>(acc23.y);                                \
    float s01x = p0 + dppf<0xB1>(p0);                                         \
    float s01y = p1 + dppf<0xB1>(p1);                                         \
    float s23x = p2 + dppf<0xB1>(p2);                                         \
    float s23y = p3 + dppf<0xB1>(p3);                                         \
    float t0 = kb0 ? s01y : s01x;                                             \
    float t1 = kb0 ? s23y : s23x;                                             \
    t0 += dppf<0x4E>(t0);                                                     \
    t1 += dppf<0x4E>(t1);                                                     \
    float tt = kb1 ? t1 : t0;                                                 \
    tt += dppf<0x128>(tt);                                                    \
    const float hn = tt;

// FULL step: runtime guards + full branch chain. Peeled first (g=0) and
// last (g=255) groups only -- covers s==0 and s==S_-2 specials, any rd.
#define STEP_FULL(g, PH, XS, CPH)                                             \
  {                                                                           \
    const int s_ = (g) * 8 + (PH);                                            \
    const float* hb = &h0_lds[bb][(PH) & 1][0];                               \
    float4 hvA = *(const float4*)(hb + rdoff);                                \
    float4 hvB = *(const float4*)(hb + rdoff + 4);                            \
    if (s_ >= 1) UP_REDUCE(((PH) + 3) & 3)                                    \
    if (w == (PH) && s_ >= 2) PL_COMBINE(((PH) + 2) & 3, s_ - 2)              \
    MAT_CORE(XS)                                                              \
    if (s_ < S_ - 2) {                                                        \
      (XS) = *(const float2*)(xgrp + ((PH) + 2) * I_);                        \
    }                                                                         \
    uP = hn * (CPH);                                                          \
    float h0n;                                                                \
    if (s_ == 0)            { hstartR = hn; h0n = 0.0f; }                     \
    else if (s_ == S_ - 2)  { h0n = fast_tanh(hn + hstartR); }                \
    else if (rd == 1)       { h0n = fast_tanh(hn + h0R); }                    \
    else if (cnt == 0)      { h0n = fast_tanh(hn + htR); htR = hn; }          \
    else                    { h0n = fast_tanh(hn); }                          \
    h0R = h0n;                                                                \
    if (wmask) h0_lds[bb][((PH) + 1) & 1][hwoff] = h0n;                       \
    cnt = (cnt + 1 == rd) ? 0 : cnt + 1;                                      \
    sync_lds();                                                               \
  }

// LEAN4: rd==4 specialization, g in [1,254]. s%4 == PH%4 is COMPILE-TIME
// (8-wide unroll): no cnt bookkeeping, no residual cndmasks.
#define STEP_LEAN4(g, PH, XS, CPH)                                            \
  {                                                                           \
    const float* hb = &h0_lds[bb][(PH) & 1][0];                               \
    float4 hvA = *(const float4*)(hb + rdoff);                                \
    float4 hvB = *(const float4*)(hb + rdoff + 4);                            \
    UP_REDUCE(((PH) + 3) & 3)                                                 \
    if (w == (PH)) PL_COMBINE(((PH) + 2) & 3, (g) * 8 + (PH) - 2)             \
    MAT_CORE(XS)                                                              \
    (XS) = *(const float2*)(xgrp + ((PH) + 2) * I_);                          \
    uP = hn * (CPH);                                                          \
    float h0n;                                                                \
    if (((PH) & 3) == 0) { h0n = fast_tanh(hn + htR); htR = hn; }             \
    else                 { h0n = fast_tanh(hn); }                             \
    if (wmask) h0_lds[bb][((PH) + 1) & 1][hwoff] = h0n;                       \
    sync_lds();                                                               \
  }

// Generic LEAN step (any rd): branchless residual, runtime cnt.
#define STEP_LEAN(g, PH, XS, CPH)                                             \
  {                                                                           \
    const float* hb = &h0_lds[bb][(PH) & 1][0];                               \
    float4 hvA = *(const float4*)(hb + rdoff);                                \
    float4 hvB = *(const float4*)(hb + rdoff + 4);                            \
    UP_REDUCE(((PH) + 3) & 3)                                                 \
    if (w == (PH)) PL_COMBINE(((PH) + 2) & 3, (g) * 8 + (PH) - 2)             \
    MAT_CORE(XS)                                                              \
    (XS) = *(const float2*)(xgrp + ((PH) + 2) * I_);                          \
    uP = hn * (CPH);                                                          \
    const bool c0 = (cnt == 0);                                               \
    float resid = rd1 ? h0R : (c0 ? htR : 0.0f);                              \
    float h0n = fast_tanh(hn + resid);                                        \
    htR = (htup && c0) ? hn : htR;                                            \
    h0R = h0n;                                                                \
    if (wmask) h0_lds[bb][((PH) + 1) & 1][hwoff] = h0n;                       \
    cnt = (cnt + 1 == rd) ? 0 : cnt + 1;                                      \
    sync_lds();                                                               \
  }

// 1024 threads = 16 waves = TWO independent batches per block (8 waves each),
// 128 blocks. Model (r0-r8, measured): wall/step = C(~330cy) + ~0.9x per-SIMD
// VALU issue; C is insensitive to wave count / barrier width / LDS traffic
// (r4, r8). C is paid once per BLOCK-step -> co-locating 2 batches amortizes
// it across 2 batch-steps. r1 tried this with a ~190-instr/wave step and
// lost (issue-dominated); the step is now ~96 instr/wave, so the issue term
// (4 waves/SIMD x 96 x 2cy = 772cy per 2 steps) plus C beats 2x the single-
// batch wall. The r8 step is used VERBATIM (proven absmax 0.0); its halved
// read burst keeps the doubled-block burst at 32 b128/CU-step.
__global__ __launch_bounds__(1024)
void rnn_kernel(
    const float* __restrict__ x, const float* __restrict__ Wi,
    const float* __restrict__ bi, const float* __restrict__ Wh,
    const float* __restrict__ bh, const float* __restrict__ Wa,
    const float* __restrict__ Wd, const int* __restrict__ rdp,
    float2* __restrict__ part)
{
    const int t = threadIdx.x;
    const int w16 = t >> 6;          // wave id 0..15
    const int bb  = w16 >> 3;        // batch slot 0/1
    const int w   = w16 & 7;         // wave ROLE 0..7 (same as 1-batch kernel)
    const int b   = blockIdx.x * BPB + bb;   // global batch
    const int l   = t & 63;
    // k-group bits b0..b3; h-group bits b4,b5; role = b0+2*b1 (final h);
    // dup bits for hn: b2,b3 (hn independent of them after the tree)
    const int  kg4   = l & 15;                       // 16 k-groups x 8 k
    const int  hg2   = (l >> 4) & 3;                 // 4 h-groups x 4 h
    const int  hbase = 16 * w + 4 * hg2;
    const int  hf    = hbase + (l & 3);              // this lane's final h
    const bool kb0   = (l & 1);
    const bool kb1   = (l >> 1) & 1;
    const bool wmask = ((l & 0xC) == 0);             // 16 writer lanes
    const int  rdoff = kg4 * CHP;                    // h-read float offset
    const int  hwoff = (hf >> 3) * CHP + (hf & 7);   // h-write float offset

    __shared__ __align__(16) float h0_lds[BPB][2][16 * CHP];
    __shared__ __align__(8)  float2 pl_lds[BPB][4][32];

    const int rd = rdp[0];
    const bool rd1  = (rd == 1);
    const bool htup = !rd1;
    if (t < BPB * 16 * CHP) h0_lds[t / (16 * CHP)][0][t % (16 * CHP)] = 0.0f;

    // Wh: lane's 8 k (k = 8*kg4 + c) x 4 h (hbase..hbase+4), packed pairs
    v2f W01[8], W23[8];
#pragma unroll
    for (int c = 0; c < 8; ++c) {
        int k = 8 * kg4 + c;
        float4 q = *(const float4*)(Wh + (size_t)k * H_ + hbase);
        W01[c] = mk2(q.x, q.y);
        W23[c] = mk2(q.z, q.w);
    }
    // Wi: lane's i-chunk {2kg4, 2kg4+1} x 4 h, packed pairs (rides k-tree)
    const int i0 = 2 * kg4;
    v2f WiF01[2], WiF23[2];
#pragma unroll
    for (int j = 0; j < 2; ++j) {
        float2 a = *(const float2*)(Wi + (size_t)(i0 + j) * H_ + hbase);
        float2 c = *(const float2*)(Wi + (size_t)(i0 + j) * H_ + hbase + 2);
        WiF01[j] = mk2(a.x, a.y);
        WiF23[j] = mk2(c.x, c.y);
    }
    // bias folded into acc init, gated to k-group 0 (enters the tree once)
    const bool k0g = (kg4 == 0);
    const v2f bias01 = k0g ? mk2(bi[hbase] + bh[hbase],
                                 bi[hbase + 1] + bh[hbase + 1]) : mk2(0.f, 0.f);
    const v2f bias23 = k0g ? mk2(bi[hbase + 2] + bh[hbase + 2],
                                 bi[hbase + 3] + bh[hbase + 3]) : mk2(0.f, 0.f);

    // Per-phase score/proj coefficient: class bit b2 selects pv (Wa) or qv
    // (Wd column for this b, phase s&7). Class-preserving reduce -> each h
    // counted exactly once per class, no duplication scale.
    const bool clsq = (l >> 2) & 1;   // b2: 0 = pv lane, 1 = qv lane
    const float waC = Wa[hf];
    float cph[8];
#pragma unroll
    for (int K = 0; K < 8; ++K)
        cph[K] = clsq ? Wd[(K << 15) + (b << 7) + hf] : waC;

    // x: each lane needs only its i-chunk (float2 at offset 2*kg4)
    const float* xgrp = x + (size_t)b * (S_ * I_) + i0;
    float2 xS0 = *(const float2*)xgrp;          // even-s slot
    float2 xS1 = *(const float2*)(xgrp + I_);   // odd-s slot

    sync_lds();

    float htR = 0.f, hstartR = 0.f, h0R = 0.f;
    float uP = 0.f;   // previous step's (hn * coef), reduced next step
    int cnt = 0;      // s % rd, incremental

    // g = 0 peeled (covers s==0 special + warm-up guards)
    {
        STEP_FULL(0, 0, xS0, cph[0])
        STEP_FULL(0, 1, xS1, cph[1])
        STEP_FULL(0, 2, xS0, cph[2])
        STEP_FULL(0, 3, xS1, cph[3])
        STEP_FULL(0, 4, xS0, cph[4])
        STEP_FULL(0, 5, xS1, cph[5])
        STEP_FULL(0, 6, xS0, cph[6])
        STEP_FULL(0, 7, xS1, cph[7])
        xgrp += 8 * I_;
    }
    if (rd == 4) {
        // hot loop, rd==4 (the bench value): cnt == PH%4 compile-time
        for (int g = 1; g < 255; ++g) {
            STEP_LEAN4(g, 0, xS0, cph[0])
            STEP_LEAN4(g, 1, xS1, cph[1])
            STEP_LEAN4(g, 2, xS0, cph[2])
            STEP_LEAN4(g, 3, xS1, cph[3])
            STEP_LEAN4(g, 4, xS0, cph[4])
            STEP_LEAN4(g, 5, xS1, cph[5])
            STEP_LEAN4(g, 6, xS0, cph[6])
            STEP_LEAN4(g, 7, xS1, cph[7])
            xgrp += 8 * I_;
        }
        cnt = 0;   // 2040 % 4 == 0, for the peeled tail
    } else {
        // generic hot loop (any rd, incl. rd==1)
        for (int g = 1; g < 255; ++g) {
            STEP_LEAN(g, 0, xS0, cph[0])
            STEP_LEAN(g, 1, xS1, cph[1])
            STEP_LEAN(g, 2, xS0, cph[2])
            STEP_LEAN(g, 3, xS1, cph[3])
            STEP_LEAN(g, 4, xS0, cph[4])
            STEP_LEAN(g, 5, xS1, cph[5])
            STEP_LEAN(g, 6, xS0, cph[6])
            STEP_LEAN(g, 7, xS1, cph[7])
            xgrp += 8 * I_;
        }
    }
    // g = 255 peeled (covers s==S_-2 special + refill clamp)
    {
        STEP_FULL(255, 0, xS0, cph[0])
        STEP_FULL(255, 1, xS1, cph[1])
        STEP_FULL(255, 2, xS0, cph[2])
        STEP_FULL(255, 3, xS1, cph[3])
        STEP_FULL(255, 4, xS0, cph[4])
        STEP_FULL(255, 5, xS1, cph[5])
        STEP_FULL(255, 6, xS0, cph[6])
        STEP_FULL(255, 7, xS1, cph[7])
    }

    // epilogue: reduce s = S-1's partial into ring 3 ((S_-1)&3), then each
    // batch slot's role-waves 0/1 combine rings 2 (s=S-2) and 3 (s=S-1).
    UP_REDUCE(3)
    sync_lds();
    if (w == 0) PL_COMBINE(2, S_ - 2)
    if (w == 1) PL_COMBINE(3, S_ - 1)
}

// out[r] = bd + sum_{f in chunk r} softmax(score)_f * d_f, chunk = 2048 flat
// (s,b) pairs with s in [8r,8r+8). ba is softmax-invariant -> omitted.
__global__ __launch_bounds__(256) void attn_kernel(
    const float2* __restrict__ part, const float* __restrict__ bd,
    float* __restrict__ out)
{
    const int r = blockIdx.x;
    const int t = threadIdx.x;
    float sc[8], dv[8];
    float mx = -1e30f;
#pragma unroll
    for (int u = 0; u < 8; ++u) {
        int f = (r << 11) + (u << 8) + t;
        float2 a = part[f];
        sc[u] = a.x;
        dv[u] = a.y;
        mx = fmaxf(mx, sc[u]);
    }
    __shared__ float redm[4], redz[4], redw[4];
#pragma unroll
    for (int off = 32; off > 0; off >>= 1) mx = fmaxf(mx, __shfl_xor(mx, off, 64));
    if ((t & 63) == 0) redm[t >> 6] = mx;
    __syncthreads();
    mx = fmaxf(fmaxf(redm[0], redm[1]), fmaxf(redm[2], redm[3]));
    float z = 0.f, wv = 0.f;
#pragma unroll
    for (int u = 0; u < 8; ++u) {
        float e = __expf(sc[u] - mx);
        z += e;
        wv += e * dv[u];
    }
#pragma unroll
    for (int off = 32; off > 0; off >>= 1) {
        z += __shfl_xor(z, off, 64);
        wv += __shfl_xor(wv, off, 64);
    }
    if ((t & 63) == 0) { redz[t >> 6] = z; redw[t >> 6] = wv; }
    __syncthreads();
    if (t == 0) {
        float Z = redz[0] + redz[1] + redz[2] + redz[3];
        float W = redw[0] + redw[1] + redw[2] + redw[3];
        out[r] = bd[0] + W / Z;
    }
}

extern "C" void kernel_launch(void* const* d_in, const int* in_sizes, int n_in,
                              void* d_out, int out_size, void* d_ws, size_t ws_size,
                              hipStream_t stream) {
    const float* x  = (const float*)d_in[0];
    const float* Wi = (const float*)d_in[1];
    const float* bi = (const float*)d_in[2];
    const float* Wh = (const float*)d_in[3];
    const float* bh = (const float*)d_in[4];
    const float* Wa = (const float*)d_in[5];
    // d_in[6] = ba: constant shift inside each softmax chunk -> no effect.
    const float* Wd = (const float*)d_in[7];
    const float* bd = (const float*)d_in[8];
    const int*  rdp = (const int*)d_in[9];

    // Workspace: one (S*B) float2 array of combined {score, d} (4 MiB)
    float2* part = (float2*)d_ws;

    rnn_kernel<<<B_ / BPB, 1024, 0, stream>>>(x, Wi, bi, Wh, bh, Wa, Wd, rdp, part);
    attn_kernel<<<B_, 256, 0, stream>>>(part, bd, (float*)d_out);
}

// Round 10
// 882.979 us; speedup vs baseline: 1.5037x; 1.5037x over previous
//
#include <hip/hip_runtime.h>
#include <math.h>

// Problem constants (fixed by the reference): B=256, S=2048, I=32, H=128, O=1
#define B_ 256
#define S_ 2048
#define I_ 32
#define H_ 128

typedef float v2f __attribute__((ext_vector_type(2)));
__device__ __forceinline__ v2f mk2(float a, float b) { v2f r; r.x = a; r.y = b; return r; }

// Packed fp32 FMA (VOP3P, gfx90a+ CDNA line): d.{x,y} += a.{x,y} * b.{x,y}.
// _lo/_hi variants splat one half of `a` to both lanes via op_sel -- used to
// broadcast a single value against a weight pair without splat movs.
__device__ __forceinline__ void pk_fma_lo(v2f& d, v2f a, v2f b) {
    asm("v_pk_fma_f32 %0, %1, %2, %0 op_sel:[0,0,0] op_sel_hi:[0,1,1]"
        : "+v"(d) : "v"(a), "v"(b));
}
__device__ __forceinline__ void pk_fma_hi(v2f& d, v2f a, v2f b) {
    asm("v_pk_fma_f32 %0, %1, %2, %0 op_sel:[1,0,0] op_sel_hi:[1,1,1]"
        : "+v"(d) : "v"(a), "v"(b));
}

// FUSED DPP-reduce stage: one v_add_f32_dpp instead of the 2-3 instruction
// sequence (v_mov 0 + v_mov_b32_dpp + v_add) that update_dpp(0,..)+add
// compiles to (old=0 defeats GCNDPPCombine). s_nop 1 covers the
// VALU-write -> DPP-read hazard (2 wait states) that the compiler's hazard
// recognizer cannot insert around inline asm. Full row/bank masks -> every
// lane sources a valid lane; bound_ctrl irrelevant.
#define FADD_DPP(out, in, CTRL)                                               \
    asm("s_nop 1\n\tv_add_f32_dpp %0, %1, %1 " CTRL                           \
        " row_mask:0xf bank_mask:0xf"                                         \
        : "=v"(out) : "v"(in));
#define FADD_DPP_IP(var, CTRL)                                                \
    asm("s_nop 1\n\tv_add_f32_dpp %0, %0, %0 " CTRL                           \
        " row_mask:0xf bank_mask:0xf"                                         \
        : "+v"(var));

// Barrier WITHOUT vmcnt(0) drain (HIP __syncthreads waits vmcnt(0) before
// s_barrier, stalling on in-flight global prefetch/stores every step).
// LDS visibility only needs lgkmcnt(0).
__device__ __forceinline__ void sync_lds() {
    asm volatile("" ::: "memory");
    asm volatile("s_waitcnt lgkmcnt(0)" ::: "memory");
    __builtin_amdgcn_s_barrier();
    asm volatile("" ::: "memory");
}

// tanh(z) = 1 - 2/(e^{2z}+1); exact limits at +-inf, abs err ~1e-7.
__device__ __forceinline__ float fast_tanh(float z) {
    float e = __expf(2.0f * z);
    return 1.0f - 2.0f / (e + 1.0f);
}

// xor16 via ds_swizzle BitMode (proven r3-r8, absmax ~0). Only in the lag-2
// combiner -- off the per-step critical path.
__device__ __forceinline__ float swz_xor16(float v) {
    return __int_as_float(__builtin_amdgcn_ds_swizzle(__float_as_int(v), 0x401F));
}

// h0 LDS layout: 16 chunks of 8 h values, chunk pitch 12 floats (48B).
// 48B stride => 16 distinct b128 addrs alias banks only 2-way (free, m136);
// the 4 lanes sharing a kg4 read the SAME addr (broadcast, no conflict).
#define CHP 12

// Packed Wh MACs for one float4 of h0 (4 consecutive k): 8 pk_fma covering
// 4 h outputs. acc01 = h-pair (hb,hb+1), acc23 = (hb+2,hb+3).
#define PKD(hv, base)                                             \
    pk_fma_lo(acc01, mk2((hv).x, (hv).y), W01[(base) + 0]);       \
    pk_fma_lo(acc23, mk2((hv).x, (hv).y), W23[(base) + 0]);       \
    pk_fma_hi(acc01, mk2((hv).x, (hv).y), W01[(base) + 1]);       \
    pk_fma_hi(acc23, mk2((hv).x, (hv).y), W23[(base) + 1]);       \
    pk_fma_lo(acc01, mk2((hv).z, (hv).w), W01[(base) + 2]);       \
    pk_fma_lo(acc23, mk2((hv).z, (hv).w), W23[(base) + 2]);       \
    pk_fma_hi(acc01, mk2((hv).z, (hv).w), W01[(base) + 3]);       \
    pk_fma_hi(acc23, mk2((hv).z, (hv).w), W23[(base) + 3]);

// Per-step score/proj partial reduce (deferred 1 step): 2 fused DPP stages
// (xor1 = b0, xor2 = b1 -- the role bits, summing the 4 roles' h).
// Remaining bits {b4,b5} go to pl_lds as 4 group-partials per class per
// wave; the lag-2 combiner absorbs them. Class bit = b2 (dup), spare dup =
// b3. Writers: b0=b1=b3=0 -> (l & 0xB) == 0, 8 lanes = 2 classes x 4 groups.
#define UP_REDUCE(RING)                                                       \
    {                                                                         \
      float r = uP;                                                           \
      FADD_DPP_IP(r, "quad_perm:[1,0,3,2]")                                   \
      FADD_DPP_IP(r, "quad_perm:[2,3,0,1]")                                   \
      if ((l & 0xB) == 0)                                                     \
        ((float*)&pl_lds[RING][(w << 2) | ((l >> 4) & 3)])[(l >> 2) & 1] = r; \
    }

// Lag-2 combiner over 32 float2 entries (8 waves x 4 groups): 5-level tree
// (xor1, xor2, xor4 via half_mirror, xor8 via ror:8, xor16 via swizzle).
// Run by wave (s&7): rotates per phase, no fixed straggler.
#define PL_COMBINE(RING, SIDX)                                                \
    {                                                                         \
      float2 pp = pl_lds[RING][l & 31];                                       \
      float px = pp.x, py = pp.y;                                             \
      FADD_DPP_IP(px, "quad_perm:[1,0,3,2]")                                  \
      FADD_DPP_IP(py, "quad_perm:[1,0,3,2]")                                  \
      FADD_DPP_IP(px, "quad_perm:[2,3,0,1]")                                  \
      FADD_DPP_IP(py, "quad_perm:[2,3,0,1]")                                  \
      FADD_DPP_IP(px, "row_half_mirror")                                      \
      FADD_DPP_IP(py, "row_half_mirror")                                      \
      FADD_DPP_IP(px, "row_ror:8")                                            \
      FADD_DPP_IP(py, "row_ror:8")                                            \
      px += swz_xor16(px);   py += swz_xor16(py);                             \
      if (l == 0) part[((SIDX) << 8) + b] = make_float2(px, py);              \
    }

// Matvec core, 4h x 8k per lane: TWO ds_read_b128. Lane bits: k-group =
// b0..b3 (kg4, 16 groups x 8 k), h-group = b4,b5; final-h role = b0 + 2*b1.
// x.Wi (i-chunk of 2 = {2kg4, 2kg4+1}) and the bias (gated kg4==0) are
// FOLDED INTO THE ACC INIT so they ride the same reduction tree.
// Tree: stage0 = PURE half_mirror (mask 7) on all 4 accs -- BEFORE any role
// select, so it never mixes h; then xor1 (+sel b0), xor2 (+sel b1), xor8
// (pure, b3). Span {7,1,2}+{8} covers all 16 k-groups; bias enters once.
// All reduce stages are single fused v_add_f32_dpp (the round-10 lever).
#define MAT_CORE(XS)                                                          \
    v2f acc01 = bias01, acc23 = bias23;                                       \
    pk_fma_lo(acc01, mk2((XS).x, (XS).y), WiF01[0]);                          \
    pk_fma_hi(acc01, mk2((XS).x, (XS).y), WiF01[1]);                          \
    pk_fma_lo(acc23, mk2((XS).x, (XS).y), WiF23[0]);                          \
    pk_fma_hi(acc23, mk2((XS).x, (XS).y), WiF23[1]);                          \
    PKD(hvA, 0) PKD(hvB, 4)                                                   \
    float p0, p1, p2, p3;                                                     \
    FADD_DPP(p0, acc01.x, "row_half_mirror")                                  \
    FADD_DPP(p1, acc01.y, "row_half_mirror")                                  \
    FADD_DPP(p2, acc23.x, "row_half_mirror")                                  \
    FADD_DPP(p3, acc23.y, "row_half_mirror")                                  \
    float s01x, s01y, s23x, s23y;                                             \
    FADD_DPP(s01x, p0, "quad_perm:[1,0,3,2]")                                 \
    FADD_DPP(s01y, p1, "quad_perm:[1,0,3,2]")                                 \
    FADD_DPP(s23x, p2, "quad_perm:[1,0,3,2]")                                 \
    FADD_DPP(s23y, p3, "quad_perm:[1,0,3,2]")                                 \
    float t0 = kb0 ? s01y : s01x;                                             \
    float t1 = kb0 ? s23y : s23x;                                             \
    FADD_DPP_IP(t0, "quad_perm:[2,3,0,1]")                                    \
    FADD_DPP_IP(t1, "quad_perm:[2,3,0,1]")                                    \
    float tt = kb1 ? t1 : t0;                                                 \
    FADD_DPP_IP(tt, "row_ror:8")                                              \
    const float hn = tt;

// FULL step: runtime guards + full branch chain. Peeled first (g=0) and
// last (g=255) groups only -- covers s==0 and s==S_-2 specials, any rd.
#define STEP_FULL(g, PH, XS, CPH)                                             \
  {                                                                           \
    const int s_ = (g) * 8 + (PH);                                            \
    const float* hb = &h0_lds[(PH) & 1][0];                                   \
    float4 hvA = *(const float4*)(hb + rdoff);                                \
    float4 hvB = *(const float4*)(hb + rdoff + 4);                            \
    if (s_ >= 1) UP_REDUCE(((PH) + 3) & 3)                                    \
    if (w == (PH) && s_ >= 2) PL_COMBINE(((PH) + 2) & 3, s_ - 2)              \
    MAT_CORE(XS)                                                              \
    if (s_ < S_ - 2) {                                                        \
      (XS) = *(const float2*)(xgrp + ((PH) + 2) * I_);                        \
    }                                                                         \
    uP = hn * (CPH);                                                          \
    float h0n;                                                                \
    if (s_ == 0)            { hstartR = hn; h0n = 0.0f; }                     \
    else if (s_ == S_ - 2)  { h0n = fast_tanh(hn + hstartR); }                \
    else if (rd == 1)       { h0n = fast_tanh(hn + h0R); }                    \
    else if (cnt == 0)      { h0n = fast_tanh(hn + htR); htR = hn; }          \
    else                    { h0n = fast_tanh(hn); }                          \
    h0R = h0n;                                                                \
    if (wmask) h0_lds[((PH) + 1) & 1][hwoff] = h0n;                           \
    cnt = (cnt + 1 == rd) ? 0 : cnt + 1;                                      \
    sync_lds();                                                               \
  }

// LEAN4: rd==4 specialization, g in [1,254]. s%4 == PH%4 is COMPILE-TIME
// (8-wide unroll): no cnt bookkeeping, no residual cndmasks.
#define STEP_LEAN4(g, PH, XS, CPH)                                            \
  {                                                                           \
    const float* hb = &h0_lds[(PH) & 1][0];                                   \
    float4 hvA = *(const float4*)(hb + rdoff);                                \
    float4 hvB = *(const float4*)(hb + rdoff + 4);                            \
    UP_REDUCE(((PH) + 3) & 3)                                                 \
    if (w == (PH)) PL_COMBINE(((PH) + 2) & 3, (g) * 8 + (PH) - 2)             \
    MAT_CORE(XS)                                                              \
    (XS) = *(const float2*)(xgrp + ((PH) + 2) * I_);                          \
    uP = hn * (CPH);                                                          \
    float h0n;                                                                \
    if (((PH) & 3) == 0) { h0n = fast_tanh(hn + htR); htR = hn; }             \
    else                 { h0n = fast_tanh(hn); }                             \
    if (wmask) h0_lds[((PH) + 1) & 1][hwoff] = h0n;                           \
    sync_lds();                                                               \
  }

// Generic LEAN step (any rd): branchless residual, runtime cnt.
#define STEP_LEAN(g, PH, XS, CPH)                                             \
  {                                                                           \
    const float* hb = &h0_lds[(PH) & 1][0];                                   \
    float4 hvA = *(const float4*)(hb + rdoff);                                \
    float4 hvB = *(const float4*)(hb + rdoff + 4);                            \
    UP_REDUCE(((PH) + 3) & 3)                                                 \
    if (w == (PH)) PL_COMBINE(((PH) + 2) & 3, (g) * 8 + (PH) - 2)             \
    MAT_CORE(XS)                                                              \
    (XS) = *(const float2*)(xgrp + ((PH) + 2) * I_);                          \
    uP = hn * (CPH);                                                          \
    const bool c0 = (cnt == 0);                                               \
    float resid = rd1 ? h0R : (c0 ? htR : 0.0f);                              \
    float h0n = fast_tanh(hn + resid);                                        \
    htR = (htup && c0) ? hn : htR;                                            \
    h0R = h0n;                                                                \
    if (wmask) h0_lds[((PH) + 1) & 1][hwoff] = h0n;                           \
    cnt = (cnt + 1 == rd) ? 0 : cnt + 1;                                      \
    sync_lds();                                                               \
  }

// 512 threads = 8 waves per batch, 1 batch per block, 256 blocks = all CUs.
// Model (r0-r9, measured): total time = S x per-step wall (sequential
// recurrence; co-location is mathematically dead, r9). Wall 712cy =
// C(~330, barrier+read-latency+chain) + issue(~380cy/SIMD). VALUBusy
// arithmetic shows ~21 instr/wave of DPP-codegen overhead (update_dpp(0,..)
// + add emits mov+mov_dpp+add; old=0 defeats GCNDPPCombine). This round
// fuses all 13 per-step reduce stages into single v_add_f32_dpp.
__global__ __launch_bounds__(512)
__attribute__((amdgpu_waves_per_eu(2, 2)))
void rnn_kernel(
    const float* __restrict__ x, const float* __restrict__ Wi,
    const float* __restrict__ bi, const float* __restrict__ Wh,
    const float* __restrict__ bh, const float* __restrict__ Wa,
    const float* __restrict__ Wd, const int* __restrict__ rdp,
    float2* __restrict__ part)
{
    const int b = blockIdx.x;
    const int t = threadIdx.x;
    const int w = t >> 6;           // wave id 0..7
    const int l = t & 63;
    // k-group bits b0..b3; h-group bits b4,b5; role = b0+2*b1 (final h);
    // dup bits for hn: b2,b3 (hn independent of them after the tree)
    const int  kg4   = l & 15;                       // 16 k-groups x 8 k
    const int  hg2   = (l >> 4) & 3;                 // 4 h-groups x 4 h
    const int  hbase = 16 * w + 4 * hg2;
    const int  hf    = hbase + (l & 3);              // this lane's final h
    const bool kb0   = (l & 1);
    const bool kb1   = (l >> 1) & 1;
    const bool wmask = ((l & 0xC) == 0);             // 16 writer lanes
    const int  rdoff = kg4 * CHP;                    // h-read float offset
    const int  hwoff = (hf >> 3) * CHP + (hf & 7);   // h-write float offset

    __shared__ __align__(16) float h0_lds[2][16 * CHP];
    __shared__ __align__(8)  float2 pl_lds[4][32];  // ring x (8 waves x 4 grp)

    const int rd = rdp[0];
    const bool rd1  = (rd == 1);
    const bool htup = !rd1;
    if (t < 16 * CHP) h0_lds[0][t] = 0.0f;

    // Wh: lane's 8 k (k = 8*kg4 + c) x 4 h (hbase..hbase+4), packed pairs
    v2f W01[8], W23[8];
#pragma unroll
    for (int c = 0; c < 8; ++c) {
        int k = 8 * kg4 + c;
        float4 q = *(const float4*)(Wh + (size_t)k * H_ + hbase);
        W01[c] = mk2(q.x, q.y);
        W23[c] = mk2(q.z, q.w);
    }
    // Wi: lane's i-chunk {2kg4, 2kg4+1} x 4 h, packed pairs (rides k-tree)
    const int i0 = 2 * kg4;
    v2f WiF01[2], WiF23[2];
#pragma unroll
    for (int j = 0; j < 2; ++j) {
        float2 a = *(const float2*)(Wi + (size_t)(i0 + j) * H_ + hbase);
        float2 c = *(const float2*)(Wi + (size_t)(i0 + j) * H_ + hbase + 2);
        WiF01[j] = mk2(a.x, a.y);
        WiF23[j] = mk2(c.x, c.y);
    }
    // bias folded into acc init, gated to k-group 0 (enters the tree once)
    const bool k0g = (kg4 == 0);
    const v2f bias01 = k0g ? mk2(bi[hbase] + bh[hbase],
                                 bi[hbase + 1] + bh[hbase + 1]) : mk2(0.f, 0.f);
    const v2f bias23 = k0g ? mk2(bi[hbase + 2] + bh[hbase + 2],
                                 bi[hbase + 3] + bh[hbase + 3]) : mk2(0.f, 0.f);

    // Per-phase score/proj coefficient: class bit b2 selects pv (Wa) or qv
    // (Wd column for this b, phase s&7). Class-preserving reduce -> each h
    // counted exactly once per class, no duplication scale.
    const bool clsq = (l >> 2) & 1;   // b2: 0 = pv lane, 1 = qv lane
    const float waC = Wa[hf];
    float cph[8];
#pragma unroll
    for (int K = 0; K < 8; ++K)
        cph[K] = clsq ? Wd[(K << 15) + (b << 7) + hf] : waC;

    // x: each lane needs only its i-chunk (float2 at offset 2*kg4)
    const float* xgrp = x + (size_t)b * (S_ * I_) + i0;
    float2 xS0 = *(const float2*)xgrp;          // even-s slot
    float2 xS1 = *(const float2*)(xgrp + I_);   // odd-s slot

    sync_lds();

    float htR = 0.f, hstartR = 0.f, h0R = 0.f;
    float uP = 0.f;   // previous step's (hn * coef), reduced next step
    int cnt = 0;      // s % rd, incremental

    // g = 0 peeled (covers s==0 special + warm-up guards)
    {
        STEP_FULL(0, 0, xS0, cph[0])
        STEP_FULL(0, 1, xS1, cph[1])
        STEP_FULL(0, 2, xS0, cph[2])
        STEP_FULL(0, 3, xS1, cph[3])
        STEP_FULL(0, 4, xS0, cph[4])
        STEP_FULL(0, 5, xS1, cph[5])
        STEP_FULL(0, 6, xS0, cph[6])
        STEP_FULL(0, 7, xS1, cph[7])
        xgrp += 8 * I_;
    }
    if (rd == 4) {
        // hot loop, rd==4 (the bench value): cnt == PH%4 compile-time
        for (int g = 1; g < 255; ++g) {
            STEP_LEAN4(g, 0, xS0, cph[0])
            STEP_LEAN4(g, 1, xS1, cph[1])
            STEP_LEAN4(g, 2, xS0, cph[2])
            STEP_LEAN4(g, 3, xS1, cph[3])
            STEP_LEAN4(g, 4, xS0, cph[4])
            STEP_LEAN4(g, 5, xS1, cph[5])
            STEP_LEAN4(g, 6, xS0, cph[6])
            STEP_LEAN4(g, 7, xS1, cph[7])
            xgrp += 8 * I_;
        }
        cnt = 0;   // 2040 % 4 == 0, for the peeled tail
    } else {
        // generic hot loop (any rd, incl. rd==1)
        for (int g = 1; g < 255; ++g) {
            STEP_LEAN(g, 0, xS0, cph[0])
            STEP_LEAN(g, 1, xS1, cph[1])
            STEP_LEAN(g, 2, xS0, cph[2])
            STEP_LEAN(g, 3, xS1, cph[3])
            STEP_LEAN(g, 4, xS0, cph[4])
            STEP_LEAN(g, 5, xS1, cph[5])
            STEP_LEAN(g, 6, xS0, cph[6])
            STEP_LEAN(g, 7, xS1, cph[7])
            xgrp += 8 * I_;
        }
    }
    // g = 255 peeled (covers s==S_-2 special + refill clamp)
    {
        STEP_FULL(255, 0, xS0, cph[0])
        STEP_FULL(255, 1, xS1, cph[1])
        STEP_FULL(255, 2, xS0, cph[2])
        STEP_FULL(255, 3, xS1, cph[3])
        STEP_FULL(255, 4, xS0, cph[4])
        STEP_FULL(255, 5, xS1, cph[5])
        STEP_FULL(255, 6, xS0, cph[6])
        STEP_FULL(255, 7, xS1, cph[7])
    }

    // epilogue: reduce s = S-1's partial into ring 3 ((S_-1)&3), then
    // combine rings 2 (s = S-2, written at top of step S-1) and 3.
    UP_REDUCE(3)
    sync_lds();
    if (w == 0) PL_COMBINE(2, S_ - 2)
    if (w == 1) PL_COMBINE(3, S_ - 1)
}

// out[r] = bd + sum_{f in chunk r} softmax(score)_f * d_f, chunk = 2048 flat
// (s,b) pairs with s in [8r,8r+8). ba is softmax-invariant -> omitted.
__global__ __launch_bounds__(256) void attn_kernel(
    const float2* __restrict__ part, const float* __restrict__ bd,
    float* __restrict__ out)
{
    const int r = blockIdx.x;
    const int t = threadIdx.x;
    float sc[8], dv[8];
    float mx = -1e30f;
#pragma unroll
    for (int u = 0; u < 8; ++u) {
        int f = (r << 11) + (u << 8) + t;
        float2 a = part[f];
        sc[u] = a.x;
        dv[u] = a.y;
        mx = fmaxf(mx, sc[u]);
    }
    __shared__ float redm[4], redz[4], redw[4];
#pragma unroll
    for (int off = 32; off > 0; off >>= 1) mx = fmaxf(mx, __shfl_xor(mx, off, 64));
    if ((t & 63) == 0) redm[t >> 6] = mx;
    __syncthreads();
    mx = fmaxf(fmaxf(redm[0], redm[1]), fmaxf(redm[2], redm[3]));
    float z = 0.f, wv = 0.f;
#pragma unroll
    for (int u = 0; u < 8; ++u) {
        float e = __expf(sc[u] - mx);
        z += e;
        wv += e * dv[u];
    }
#pragma unroll
    for (int off = 32; off > 0; off >>= 1) {
        z += __shfl_xor(z, off, 64);
        wv += __shfl_xor(wv, off, 64);
    }
    if ((t & 63) == 0) { redz[t >> 6] = z; redw[t >> 6] = wv; }
    __syncthreads();
    if (t == 0) {
        float Z = redz[0] + redz[1] + redz[2] + redz[3];
        float W = redw[0] + redw[1] + redw[2] + redw[3];
        out[r] = bd[0] + W / Z;
    }
}

extern "C" void kernel_launch(void* const* d_in, const int* in_sizes, int n_in,
                              void* d_out, int out_size, void* d_ws, size_t ws_size,
                              hipStream_t stream) {
    const float* x  = (const float*)d_in[0];
    const float* Wi = (const float*)d_in[1];
    const float* bi = (const float*)d_in[2];
    const float* Wh = (const float*)d_in[3];
    const float* bh = (const float*)d_in[4];
    const float* Wa = (const float*)d_in[5];
    // d_in[6] = ba: constant shift inside each softmax chunk -> no effect.
    const float* Wd = (const float*)d_in[7];
    const float* bd = (const float*)d_in[8];
    const int*  rdp = (const int*)d_in[9];

    // Workspace: one (S*B) float2 array of combined {score, d} (4 MiB)
    float2* part = (float2*)d_ws;

    rnn_kernel<<<B_, 512, 0, stream>>>(x, Wi, bi, Wh, bh, Wa, Wd, rdp, part);
    attn_kernel<<<B_, 256, 0, stream>>>(part, bd, (float*)d_out);
}